// Round 6
// baseline (1101.380 us; speedup 1.0000x reference)
//
#include <hip/hip_runtime.h>
#include <hip/hip_bf16.h>
#include <hip/hip_fp16.h>

#define F_IN 512
#define BSH 8                    // 256 dest nodes per bucket
#define BN  (1 << BSH)
#define NCH 256                  // edge chunks (one block each in count/place)
#define MAXBK 512                // max buckets supported (n <= 131072)

// ---------- pass 1: per-(bucket,chunk) edge counts via LDS histogram ----------
__global__ __launch_bounds__(256) void k_count(
    const int* __restrict__ col, int* __restrict__ cnt, int E, int nbk, int cs)
{
    __shared__ int hist[MAXBK];
    int c = blockIdx.x, t = threadIdx.x;
    for (int b = t; b < MAXBK; b += 256) hist[b] = 0;
    __syncthreads();
    int s = c * cs, e = min(s + cs, E);
    for (int i = s + t; i < e; i += 256) atomicAdd(&hist[col[i] >> BSH], 1);
    __syncthreads();
    for (int b = t; b < nbk; b += 256) cnt[b * NCH + c] = hist[b];
}

// ---------- scan A: per-bucket exclusive scan over chunks; totals out ----------
__global__ __launch_bounds__(256) void k_scan1(
    const int* __restrict__ cnt, int* __restrict__ off, int* __restrict__ total)
{
    __shared__ int sm[NCH];
    int b = blockIdx.x, t = threadIdx.x;
    int v = cnt[b * NCH + t];
    sm[t] = v; __syncthreads();
    #pragma unroll
    for (int o = 1; o < NCH; o <<= 1) {
        int xv = (t >= o) ? sm[t - o] : 0;
        __syncthreads();
        sm[t] += xv; __syncthreads();
    }
    off[b * NCH + t] = sm[t] - v;
    if (t == NCH - 1) total[b] = sm[t];
}

// ---------- scan B: exclusive scan of bucket totals -> base ----------
__global__ __launch_bounds__(512) void k_scan2(
    const int* __restrict__ total, int* __restrict__ base, int nbk)
{
    __shared__ int sm[512];
    int t = threadIdx.x;
    int v = (t < nbk) ? total[t] : 0;
    sm[t] = v; __syncthreads();
    #pragma unroll
    for (int o = 1; o < 512; o <<= 1) {
        int xv = (t >= o) ? sm[t - o] : 0;
        __syncthreads();
        sm[t] += xv; __syncthreads();
    }
    if (t < nbk) base[t] = sm[t] - v;
}

// ---------- pass 2: place packed entries; LDS cursors, block-private regions ----------
__global__ __launch_bounds__(256) void k_place(
    const int* __restrict__ row, const int* __restrict__ col,
    const int* __restrict__ off, const int* __restrict__ base,
    int* __restrict__ entries, int E, int nbk, int cs)
{
    __shared__ int cur[MAXBK];
    int c = blockIdx.x, t = threadIdx.x;
    for (int b = t; b < nbk; b += 256) cur[b] = base[b] + off[b * NCH + c];
    __syncthreads();
    int s = c * cs, e = min(s + cs, E);
    for (int i = s + t; i < e; i += 256) {
        int cl = col[i];
        int b  = cl >> BSH;
        int p  = atomicAdd(&cur[b], 1);
        entries[p] = (row[i] << BSH) | (cl & (BN - 1));
    }
}

// ---------- per-bucket degree -> dinv = rsqrt(deg+1) ----------
__global__ __launch_bounds__(256) void k_bdeg(
    const int* __restrict__ entries, const int* __restrict__ base,
    const int* __restrict__ total, float* __restrict__ dinv, int n)
{
    __shared__ int cnt[BN];
    int b = blockIdx.x, t = threadIdx.x;
    cnt[t] = 0; __syncthreads();
    int s = base[b], e = s + total[b];
    for (int i = s + t; i < e; i += 256) atomicAdd(&cnt[entries[i] & (BN - 1)], 1);
    __syncthreads();
    int g = (b << BSH) + t;
    if (g < n) dinv[g] = rsqrtf((float)(cnt[t] + 1));
}

// ---------- hs = (x @ W1) * dinv[node], f16; wave-per-node ----------
__global__ __launch_bounds__(256) void k_gemm1(
    const float* __restrict__ x, const float* __restrict__ W1,
    const float* __restrict__ dinv, __half2* __restrict__ hs, int n)
{
    __shared__ float red[4][64 * 17];
    const int lane = threadIdx.x & 63;
    const int wib  = threadIdx.x >> 6;
    const int wave = blockIdx.x * (blockDim.x >> 6) + wib;
    const int nw   = gridDim.x * (blockDim.x >> 6);
    float* rb = red[wib];

    float w[128];
    #pragma unroll
    for (int i = 0; i < 32; ++i) {
        float4 t = ((const float4*)W1)[lane * 32 + i];
        w[4*i+0] = t.x; w[4*i+1] = t.y; w[4*i+2] = t.z; w[4*i+3] = t.w;
    }
    const int q  = lane >> 4;
    const int jj = lane & 15;

    for (int node = wave; node < n; node += nw) {
        const float4* xr = (const float4*)(x + (size_t)node * F_IN);
        float4 a = xr[lane * 2];
        float4 b = xr[lane * 2 + 1];
        float xs[8] = {a.x, a.y, a.z, a.w, b.x, b.y, b.z, b.w};

        float p[16];
        #pragma unroll
        for (int j = 0; j < 16; ++j) p[j] = 0.f;
        #pragma unroll
        for (int i = 0; i < 8; ++i)
            #pragma unroll
            for (int j = 0; j < 16; ++j)
                p[j] = fmaf(xs[i], w[i * 16 + j], p[j]);

        #pragma unroll
        for (int j = 0; j < 16; ++j) rb[lane * 17 + j] = p[j];
        __asm__ volatile("s_waitcnt lgkmcnt(0)" ::: "memory");
        float s = 0.f;
        #pragma unroll
        for (int i = 0; i < 16; ++i) s += rb[(q * 16 + i) * 17 + jj];
        s += __shfl_down(s, 32);
        s += __shfl_down(s, 16);

        float sv = s * dinv[node];
        float sn = __shfl_down(sv, 1);
        if (lane < 16 && (lane & 1) == 0)
            hs[node * 8 + (lane >> 1)] = __halves2half2(__float2half(sv), __float2half(sn));
    }
}

// ---------- agg layer 1 (fused gemm2): LDS fp32 accumulate, no global atomics ----------
__global__ __launch_bounds__(512) void k_agg1(
    const int* __restrict__ entries, const int* __restrict__ base,
    const int* __restrict__ total, const __half2* __restrict__ hs,
    const float* __restrict__ dinv, const float* __restrict__ b1,
    const float* __restrict__ W2, __half2* __restrict__ hs2, int n)
{
    __shared__ float accf[BN * 17];
    __shared__ float w2s[256];
    int b = blockIdx.x, t = threadIdx.x;
    int node0 = b << BSH;
    if (t < 256) w2s[t] = W2[t];
    const __half* hsv = (const __half*)hs;
    for (int k = t; k < BN * 16; k += 512) {
        int i = k >> 4, j = k & 15, g = node0 + i;
        accf[i * 17 + j] = (g < n) ? __half2float(hsv[g * 16 + j]) : 0.f;
    }
    __syncthreads();

    int s = base[b], e = s + total[b];
    for (int i = s + t; i < e; i += 512) {
        int en = entries[i];
        int r  = en >> BSH;
        int cl = en & (BN - 1);
        int4 lo = ((const int4*)hs)[r * 2];
        int4 hi = ((const int4*)hs)[r * 2 + 1];
        __half2 q[8];
        *(int4*)q       = lo;
        *(int4*)(q + 4) = hi;
        float* ap = accf + cl * 17;
        #pragma unroll
        for (int jp = 0; jp < 8; ++jp) {
            float2 f = __half22float2(q[jp]);
            atomicAdd(ap + 2 * jp,     f.x);
            atomicAdd(ap + 2 * jp + 1, f.y);
        }
    }
    __syncthreads();

    if (t < 256) {
        int g = node0 + t;
        if (g < n) {
            float di = dinv[g];
            float v[16];
            #pragma unroll
            for (int k = 0; k < 16; ++k)
                v[k] = fmaxf(accf[t * 17 + k] * di + b1[k], 0.f);
            __half2 op[8];
            #pragma unroll
            for (int jp = 0; jp < 8; ++jp) {
                float h0 = 0.f, h1 = 0.f;
                #pragma unroll
                for (int k = 0; k < 16; ++k) {
                    h0 = fmaf(v[k], w2s[k * 16 + 2 * jp],     h0);
                    h1 = fmaf(v[k], w2s[k * 16 + 2 * jp + 1], h1);
                }
                op[jp] = __halves2half2(__float2half(h0 * di), __float2half(h1 * di));
            }
            ((int4*)hs2)[g * 2]     = *(int4*)op;
            ((int4*)hs2)[g * 2 + 1] = *(int4*)(op + 4);
        }
    }
}

// ---------- agg layer 2 (fused bias + log_softmax -> out) ----------
__global__ __launch_bounds__(512) void k_agg2(
    const int* __restrict__ entries, const int* __restrict__ base,
    const int* __restrict__ total, const __half2* __restrict__ hs2,
    const float* __restrict__ dinv, const float* __restrict__ b2,
    float* __restrict__ out, int n)
{
    __shared__ float accf[BN * 17];
    int b = blockIdx.x, t = threadIdx.x;
    int node0 = b << BSH;
    const __half* hsv = (const __half*)hs2;
    for (int k = t; k < BN * 16; k += 512) {
        int i = k >> 4, j = k & 15, g = node0 + i;
        accf[i * 17 + j] = (g < n) ? __half2float(hsv[g * 16 + j]) : 0.f;
    }
    __syncthreads();

    int s = base[b], e = s + total[b];
    for (int i = s + t; i < e; i += 512) {
        int en = entries[i];
        int r  = en >> BSH;
        int cl = en & (BN - 1);
        int4 lo = ((const int4*)hs2)[r * 2];
        int4 hi = ((const int4*)hs2)[r * 2 + 1];
        __half2 q[8];
        *(int4*)q       = lo;
        *(int4*)(q + 4) = hi;
        float* ap = accf + cl * 17;
        #pragma unroll
        for (int jp = 0; jp < 8; ++jp) {
            float2 f = __half22float2(q[jp]);
            atomicAdd(ap + 2 * jp,     f.x);
            atomicAdd(ap + 2 * jp + 1, f.y);
        }
    }
    __syncthreads();

    if (t < 256) {
        int g = node0 + t;
        if (g < n) {
            float di = dinv[g];
            float v[16];
            float m = -1e30f;
            #pragma unroll
            for (int j = 0; j < 16; ++j) {
                v[j] = accf[t * 17 + j] * di + b2[j];
                m = fmaxf(m, v[j]);
            }
            float sum = 0.f;
            #pragma unroll
            for (int j = 0; j < 16; ++j) sum += expf(v[j] - m);
            float lse = m + logf(sum);
            float4 o[4];
            #pragma unroll
            for (int j = 0; j < 16; ++j) ((float*)o)[j] = v[j] - lse;
            float4* op = (float4*)(out + (size_t)g * 16);
            #pragma unroll
            for (int q2 = 0; q2 < 4; ++q2) op[q2] = o[q2];
        }
    }
}

extern "C" void kernel_launch(void* const* d_in, const int* in_sizes, int n_in,
                              void* d_out, int out_size, void* d_ws, size_t ws_size,
                              hipStream_t stream)
{
    const float* x  = (const float*)d_in[0];
    const int*   ei = (const int*)d_in[1];   // [2, E]: row then col
    const float* W1 = (const float*)d_in[2];
    const float* b1 = (const float*)d_in[3];
    const float* W2 = (const float*)d_in[4];
    const float* b2 = (const float*)d_in[5];
    float* out = (float*)d_out;

    const int n   = in_sizes[0] / F_IN;          // 100000
    const int E   = in_sizes[1] / 2;             // 3.2M
    const int nbk = (n + BN - 1) >> BSH;         // 391 buckets
    const int cs  = (E + NCH - 1) / NCH;         // 12500 edges/chunk

    // ws: cnt | off | total | base | dinv | entries | hs | hs2
    char* ws = (char*)d_ws;
    size_t szC = (((size_t)nbk * NCH * 4) + 511) & ~(size_t)511;
    size_t szT = 4096;
    size_t szN = (((size_t)n * 4) + 511) & ~(size_t)511;
    size_t szE = (((size_t)E * 4) + 511) & ~(size_t)511;
    size_t szH = (((size_t)n * 16 * 2) + 511) & ~(size_t)511;
    int*     cnt     = (int*)(ws);
    int*     off     = (int*)(ws + szC);
    int*     total   = (int*)(ws + 2 * szC);
    int*     base    = (int*)(ws + 2 * szC + szT);
    float*   dinv    = (float*)(ws + 2 * szC + 2 * szT);
    int*     entries = (int*)(ws + 2 * szC + 2 * szT + szN);
    __half2* hs      = (__half2*)(ws + 2 * szC + 2 * szT + szN + szE);
    __half2* hs2     = (__half2*)(ws + 2 * szC + 2 * szT + szN + szE + szH);

    // build CSR-ish bucketed edge list (no global atomics anywhere)
    k_count<<<NCH, 256, 0, stream>>>(ei + E, cnt, E, nbk, cs);
    k_scan1<<<nbk, 256, 0, stream>>>(cnt, off, total);
    k_scan2<<<1, 512, 0, stream>>>(total, base, nbk);
    k_place<<<NCH, 256, 0, stream>>>(ei, ei + E, off, base, entries, E, nbk, cs);
    k_bdeg <<<nbk, 256, 0, stream>>>(entries, base, total, dinv, n);

    // layer 1 dense part
    k_gemm1<<<2048, 256, 0, stream>>>(x, W1, dinv, hs, n);

    // aggregation passes (layer-2 gemm and final epilogue fused in)
    k_agg1<<<nbk, 512, 0, stream>>>(entries, base, total, hs, dinv, b1, W2, hs2, n);
    k_agg2<<<nbk, 512, 0, stream>>>(entries, base, total, hs2, dinv, b2, out, n);
}